// Round 4
// baseline (346.610 us; speedup 1.0000x reference)
//
#include <hip/hip_runtime.h>
#include <math.h>

// x [64,4096,64] fp32, embedding [512,64] fp32
#define N_ROWS   262144
#define DIM      64
#define KCODES   512
#define NTHREADS 256
#define NBLOCKS  256
#define ROWS_PER_BLOCK (N_ROWS / NBLOCKS)    // 1024
#define ROWS_PER_WAVE  (ROWS_PER_BLOCK / 4)  // 256
#define TILES_PER_WAVE (ROWS_PER_WAVE / 32)  // 8
#define ESTR     72          // bf16 stride: 144 B, 16B-multiple (b128-aligned frags)
#define MARGIN   2e-3f       // flag threshold; 3-term split error bound ~5e-4

typedef float f32x4 __attribute__((ext_vector_type(4)));
typedef short s16x8 __attribute__((ext_vector_type(8)));
typedef short s16x4 __attribute__((ext_vector_type(4)));

// ws layout (bytes):
//   0       esq[512]        f32   (2048)
//   2048    counts[512]     int   (2048)
//   4096    lossAdj         f32   (4)
//   4608    flagmask[8192]  u32   (32768)
//   37376   idx[262144]     u16   (524288)
//   561664  lossPart[1024]  f32   (4096)

__device__ __forceinline__ unsigned short f2bf(float f) {
    unsigned u = __float_as_uint(f);
    unsigned r = u + 0x7fffu + ((u >> 16) & 1u);   // RNE
    return (unsigned short)(r >> 16);
}
__device__ __forceinline__ float bf2f(unsigned short h) {
    return __uint_as_float(((unsigned)h) << 16);
}

__global__ __launch_bounds__(512) void vq_prep(const float* __restrict__ emb,
                                               float* __restrict__ esq,
                                               int* __restrict__ counts,
                                               float* __restrict__ lossAdj,
                                               unsigned* __restrict__ mask) {
    int k = threadIdx.x;                       // 512 threads, 1 block
    const float* e = emb + (size_t)k * DIM;
    float s = 0.f;
    #pragma unroll
    for (int d = 0; d < DIM; ++d) s += e[d] * e[d];   // identical to round-1 prep
    esq[k] = s;
    counts[k] = 0;
    #pragma unroll
    for (int i = 0; i < 16; ++i) mask[k * 16 + i] = 0u;
    if (k == 0) *lossAdj = 0.f;
}

__global__ __launch_bounds__(NTHREADS, 1) void vq_main(
    const float* __restrict__ x, const float* __restrict__ emb,
    const float* __restrict__ g_esq,
    unsigned short* __restrict__ g_idx, float* __restrict__ g_lossPart,
    unsigned* __restrict__ g_mask, float* __restrict__ out)
{
    __shared__ unsigned short ehs[KCODES * ESTR];     // 73728 B
    __shared__ unsigned short els[KCODES * ESTR];     // 73728 B
    __shared__ float esq_s[KCODES];                   // 2048 B
    __shared__ int idxflg[4 * 32];                    // per-wave scratch

    const int tid  = threadIdx.x;
    const int w    = tid >> 6;
    const int lane = tid & 63;
    const int m    = lane & 15;
    const int q    = lane >> 4;

    // ---- stage + split codebook into LDS (once per block) ----
    #pragma unroll 4
    for (int i = 0; i < 32; ++i) {
        int f = tid + NTHREADS * i;                   // 0..8191
        int code = f >> 4, d4 = (f & 15) * 4;
        f32x4 v = *(const f32x4*)&emb[(size_t)code * DIM + d4];
        s16x4 hv, lv;
        #pragma unroll
        for (int j = 0; j < 4; ++j) {
            unsigned short h = f2bf(v[j]);
            hv[j] = (short)h;
            lv[j] = (short)f2bf(v[j] - bf2f(h));
        }
        *(s16x4*)&ehs[code * ESTR + d4] = hv;
        *(s16x4*)&els[code * ESTR + d4] = lv;
    }
    esq_s[tid]       = g_esq[tid];
    esq_s[tid + 256] = g_esq[tid + 256];
    __syncthreads();                                  // the ONLY barrier

    float lpart = 0.f;
    const int waveRow0 = blockIdx.x * ROWS_PER_BLOCK + w * ROWS_PER_WAVE;

    for (int t = 0; t < TILES_PER_WAVE; ++t) {
        const int T0 = waveRow0 + t * 32;

        // ---- load x global->reg, convert to bf16 hi/lo A-frags ----
        s16x8 axh[2][2], axl[2][2];                   // [rowgroup][kc]
        #pragma unroll
        for (int g = 0; g < 2; ++g) {
            const float* px = &x[(size_t)(T0 + g * 16 + m) * DIM + q * 8];
            #pragma unroll
            for (int kc = 0; kc < 2; ++kc) {
                f32x4 v0 = *(const f32x4*)&px[kc * 32];
                f32x4 v1 = *(const f32x4*)&px[kc * 32 + 4];
                s16x8 h, l;
                #pragma unroll
                for (int j = 0; j < 4; ++j) {
                    unsigned short hb = f2bf(v0[j]);
                    h[j] = (short)hb; l[j] = (short)f2bf(v0[j] - bf2f(hb));
                    unsigned short hb1 = f2bf(v1[j]);
                    h[4 + j] = (short)hb1; l[4 + j] = (short)f2bf(v1[j] - bf2f(hb1));
                }
                axh[g][kc] = h; axl[g][kc] = l;
            }
        }

        f32x4 acc0[32], acc1[32];
        #pragma unroll
        for (int a = 0; a < 32; ++a) { acc0[a] = (f32x4){0,0,0,0}; acc1[a] = (f32x4){0,0,0,0}; }

        // ---- barrier-free K-loop over all 512 codes ----
        #pragma unroll
        for (int ct = 0; ct < 32; ++ct) {
            const int bo = (ct * 16 + m) * ESTR + q * 8;
            s16x8 bh0 = *(const s16x8*)&ehs[bo];
            s16x8 bl0 = *(const s16x8*)&els[bo];
            s16x8 bh1 = *(const s16x8*)&ehs[bo + 32];
            s16x8 bl1 = *(const s16x8*)&els[bo + 32];
            acc0[ct] = __builtin_amdgcn_mfma_f32_16x16x32_bf16(axh[0][0], bh0, acc0[ct], 0, 0, 0);
            acc0[ct] = __builtin_amdgcn_mfma_f32_16x16x32_bf16(axl[0][0], bh0, acc0[ct], 0, 0, 0);
            acc0[ct] = __builtin_amdgcn_mfma_f32_16x16x32_bf16(axh[0][0], bl0, acc0[ct], 0, 0, 0);
            acc0[ct] = __builtin_amdgcn_mfma_f32_16x16x32_bf16(axh[0][1], bh1, acc0[ct], 0, 0, 0);
            acc0[ct] = __builtin_amdgcn_mfma_f32_16x16x32_bf16(axl[0][1], bh1, acc0[ct], 0, 0, 0);
            acc0[ct] = __builtin_amdgcn_mfma_f32_16x16x32_bf16(axh[0][1], bl1, acc0[ct], 0, 0, 0);
            acc1[ct] = __builtin_amdgcn_mfma_f32_16x16x32_bf16(axh[1][0], bh0, acc1[ct], 0, 0, 0);
            acc1[ct] = __builtin_amdgcn_mfma_f32_16x16x32_bf16(axl[1][0], bh0, acc1[ct], 0, 0, 0);
            acc1[ct] = __builtin_amdgcn_mfma_f32_16x16x32_bf16(axh[1][0], bl0, acc1[ct], 0, 0, 0);
            acc1[ct] = __builtin_amdgcn_mfma_f32_16x16x32_bf16(axh[1][1], bh1, acc1[ct], 0, 0, 0);
            acc1[ct] = __builtin_amdgcn_mfma_f32_16x16x32_bf16(axl[1][1], bh1, acc1[ct], 0, 0, 0);
            acc1[ct] = __builtin_amdgcn_mfma_f32_16x16x32_bf16(axh[1][1], bl1, acc1[ct], 0, 0, 0);
        }

        // ---- argmin + second-best per rowgroup (C: row=q*4+r, col=a*16+m) ----
        #pragma unroll
        for (int g = 0; g < 2; ++g) {
            float b1[4], b2[4]; int i1[4];
            #pragma unroll
            for (int r = 0; r < 4; ++r) { b1[r] = 3.4e38f; b2[r] = 3.4e38f; i1[r] = 0; }
            #pragma unroll
            for (int a = 0; a < 32; ++a) {
                int col = a * 16 + m;                 // ascending: first-min tie-break
                float e2 = esq_s[col];
                #pragma unroll
                for (int r = 0; r < 4; ++r) {
                    f32x4 av = (g == 0) ? acc0[a] : acc1[a];
                    float dist = e2 - 2.f * av[r];
                    if (dist < b1[r]) { b2[r] = b1[r]; b1[r] = dist; i1[r] = col; }
                    else if (dist < b2[r]) b2[r] = dist;
                }
            }
            #pragma unroll
            for (int s = 1; s < 16; s <<= 1) {
                #pragma unroll
                for (int r = 0; r < 4; ++r) {
                    float ob1 = __shfl_xor(b1[r], s);
                    int   oi1 = __shfl_xor(i1[r], s);
                    float ob2 = __shfl_xor(b2[r], s);
                    bool owin = (ob1 < b1[r]) || (ob1 == b1[r] && oi1 < i1[r]);
                    float lb1 = owin ? b1[r] : ob1;
                    b2[r] = fminf(fminf(b2[r], ob2), lb1);
                    if (owin) { b1[r] = ob1; i1[r] = oi1; }
                }
            }
            if (m == 0) {
                #pragma unroll
                for (int r = 0; r < 4; ++r) {
                    int fl = (b2[r] - b1[r] < MARGIN) ? 1 : 0;
                    idxflg[w * 32 + g * 16 + q * 4 + r] = i1[r] | (fl << 16);
                    if (fl) {
                        int grow = T0 + g * 16 + q * 4 + r;
                        atomicOr(&g_mask[grow >> 5], 1u << (grow & 31));   // rare
                    }
                }
            }
        }
        __threadfence_block();   // same-wave LDS visibility (lgkmcnt drain)

        // ---- epilogue: idx store, q_st + loss (round-1 op order) ----
        #pragma unroll
        for (int g = 0; g < 2; ++g) {
            int row16 = lane >> 2;
            int pk  = idxflg[w * 32 + g * 16 + row16];
            int row = T0 + g * 16 + row16;
            int ki  = pk & 0xffff;
            int fl  = pk >> 16;
            if ((lane & 3) == 0) g_idx[row] = (unsigned short)ki;
            if (!fl) {
                int c = (lane & 3) * 16;
                const float* xr = &x[(size_t)row * DIM + c];
                const float* er = &emb[(size_t)ki * DIM + c];
                #pragma unroll
                for (int u = 0; u < 4; ++u) {
                    f32x4 xv = *(const f32x4*)&xr[4 * u];
                    f32x4 ev = *(const f32x4*)&er[4 * u];
                    f32x4 fd, o;
                    #pragma unroll
                    for (int j = 0; j < 4; ++j) {
                        fd[j] = ev[j] - xv[j];
                        o[j]  = xv[j] + fd[j];
                        lpart += fd[j] * fd[j];
                    }
                    *(f32x4*)&out[(size_t)row * DIM + c + 4 * u] = o;
                }
            }
        }
    }

    // per-wave loss partial (no atomics)
    #pragma unroll
    for (int s = 32; s > 0; s >>= 1) lpart += __shfl_down(lpart, s);
    if (lane == 0) g_lossPart[blockIdx.x * 4 + w] = lpart;
}

// Exact fp32 re-resolution of flagged rows — replicates round-1 math bit-for-bit.
__global__ __launch_bounds__(256) void vq_cleanup(
    const float* __restrict__ x, const float* __restrict__ emb,
    const float* __restrict__ g_esq, unsigned short* __restrict__ g_idx,
    float* __restrict__ lossAdj, const unsigned* __restrict__ g_mask,
    float* __restrict__ out)
{
    int w    = blockIdx.x * 4 + (threadIdx.x >> 6);   // 0..4095, 64 rows each
    int lane = threadIdx.x & 63;
    unsigned m0 = g_mask[w * 2], m1 = g_mask[w * 2 + 1];
    unsigned long long bits = ((unsigned long long)m1 << 32) | m0;
    while (bits) {
        int b = __ffsll((unsigned long long)bits) - 1;
        bits &= bits - 1;
        int row = w * 64 + b;
        const float* xr = &x[(size_t)row * DIM];
        float best = 3.4e38f; int bidx = 0;
        #pragma unroll
        for (int j = 0; j < 8; ++j) {
            int c = lane * 8 + j;
            const float* er = &emb[(size_t)c * DIM];
            float dot = 0.f;
            #pragma unroll
            for (int d = 0; d < DIM; ++d) dot = fmaf(xr[d], er[d], dot);
            float dist = g_esq[c] - 2.f * dot;         // round-1 formula/order
            if (dist < best) { best = dist; bidx = c; }
        }
        #pragma unroll
        for (int s = 1; s < 64; s <<= 1) {
            float ob = __shfl_xor(best, s);
            int   oi = __shfl_xor(bidx, s);
            if (ob < best || (ob == best && oi < bidx)) { best = ob; bidx = oi; }
        }
        float xv = xr[lane];
        float ev = emb[(size_t)bidx * DIM + lane];
        float f  = ev - xv;
        out[(size_t)row * DIM + lane] = xv + f;
        float lp = f * f;
        #pragma unroll
        for (int s = 1; s < 64; s <<= 1) lp += __shfl_xor(lp, s);
        if (lane == 0) {
            atomicAdd(lossAdj, lp);                    // rare
            g_idx[row] = (unsigned short)bidx;
        }
    }
}

// Low-contention histogram: LDS per-block, then <=512 global adds per block.
__global__ __launch_bounds__(256) void vq_hist(const unsigned short* __restrict__ g_idx,
                                               int* __restrict__ counts) {
    __shared__ int h[KCODES];
    int t = threadIdx.x;
    h[t] = 0; h[t + 256] = 0;
    __syncthreads();
    const unsigned short* p = g_idx + (size_t)blockIdx.x * 4096;
    #pragma unroll
    for (int i = 0; i < 16; ++i)
        atomicAdd(&h[p[t + 256 * i]], 1);
    __syncthreads();
    int v0 = h[t], v1 = h[t + 256];
    if (v0) atomicAdd(&counts[t], v0);
    if (v1) atomicAdd(&counts[t + 256], v1);
}

__global__ __launch_bounds__(512) void vq_final(const int* __restrict__ counts,
                                                const float* __restrict__ lossPart,
                                                const float* __restrict__ lossAdj,
                                                float* __restrict__ out) {
    __shared__ float redp[8];
    __shared__ float redl[8];
    int k = threadIdx.x;
    float p = (float)counts[k] * (1.f / 262144.f);
    float t = p * logf(p + 1e-10f);
    float l = lossPart[k] + lossPart[k + 512];
    #pragma unroll
    for (int off = 32; off > 0; off >>= 1) {
        t += __shfl_down(t, off);
        l += __shfl_down(l, off);
    }
    if ((k & 63) == 0) { redp[k >> 6] = t; redl[k >> 6] = l; }
    __syncthreads();
    if (k == 0) {
        float s = 0.f, ls = 0.f;
        #pragma unroll
        for (int i = 0; i < 8; ++i) { s += redp[i]; ls += redl[i]; }
        out[16777216] = (ls + *lossAdj) * (0.25f / 16777216.f);
        out[16777217] = expf(-s);
    }
}

extern "C" void kernel_launch(void* const* d_in, const int* in_sizes, int n_in,
                              void* d_out, int out_size, void* d_ws, size_t ws_size,
                              hipStream_t stream) {
    const float* x   = (const float*)d_in[0];
    const float* emb = (const float*)d_in[1];
    float* out = (float*)d_out;

    char* ws = (char*)d_ws;
    float*          esq      = (float*)(ws + 0);
    int*            counts   = (int*)(ws + 2048);
    float*          lossAdj  = (float*)(ws + 4096);
    unsigned*       mask     = (unsigned*)(ws + 4608);
    unsigned short* gidx     = (unsigned short*)(ws + 37376);
    float*          lossPart = (float*)(ws + 561664);

    vq_prep<<<1, 512, 0, stream>>>(emb, esq, counts, lossAdj, mask);
    vq_main<<<NBLOCKS, NTHREADS, 0, stream>>>(x, emb, esq, gidx, lossPart, mask, out);
    vq_cleanup<<<1024, 256, 0, stream>>>(x, emb, esq, gidx, lossAdj, mask, out);
    vq_hist<<<64, 256, 0, stream>>>(gidx, counts);
    vq_final<<<1, 512, 0, stream>>>(counts, lossPart, lossAdj, out);
}

// Round 5
// 266.429 us; speedup vs baseline: 1.3009x; 1.3009x over previous
//
#include <hip/hip_runtime.h>
#include <math.h>

// x [64,4096,64] fp32, embedding [512,64] fp32
#define N_ROWS   262144
#define DIM      64
#define KCODES   512
#define NTHREADS 512                 // 8 waves
#define NBLOCKS  256                 // 1 block/CU
#define TILES    4                   // 32-row tiles per wave -> 1024 rows/block
#define ESTR     72                  // bf16 LDS stride (144 B)
#define MARGIN   2e-3f               // 3-term split error bound ~1e-3

typedef float f32x4 __attribute__((ext_vector_type(4)));
typedef short s16x8 __attribute__((ext_vector_type(8)));
typedef short s16x4 __attribute__((ext_vector_type(4)));

// ws layout (bytes):
//   0       flagmask[8192]   u32  (32768)
//   32768   idx[262144]      u16  (524288)
//   557056  lossPart[256]    f32  (1024)
//   558080  lossPost[64]     f32  (256)
//   558336  counts2d[64*512] int  (131072)
// total ~689 KB

__device__ __forceinline__ unsigned short f2bf(float f) {
    unsigned u = __float_as_uint(f);
    unsigned r = u + 0x7fffu + ((u >> 16) & 1u);   // RNE
    return (unsigned short)(r >> 16);
}
__device__ __forceinline__ float bf2f(unsigned short h) {
    return __uint_as_float(((unsigned)h) << 16);
}

__global__ __launch_bounds__(NTHREADS, 2) void vq_main(
    const float* __restrict__ x, const float* __restrict__ emb,
    unsigned short* __restrict__ g_idx, float* __restrict__ g_lossPart,
    unsigned* __restrict__ g_mask, float* __restrict__ out)
{
    __shared__ unsigned short ehs[KCODES * ESTR];   // 73728 B
    __shared__ unsigned short els[KCODES * ESTR];   // 73728 B
    __shared__ float esq_s[KCODES];                 // 2048 B
    __shared__ unsigned short idx_sh[8][32];
    __shared__ unsigned short flg_sh[8][32];
    __shared__ float wred[8];

    const int tid  = threadIdx.x;
    const int w    = tid >> 6;
    const int lane = tid & 63;
    const int m    = lane & 15;
    const int q    = lane >> 4;

    // ---- per-block prep: zero own mask slice (rows of this block only) ----
    if (tid < 32) g_mask[blockIdx.x * 32 + tid] = 0u;

    // ---- esq: thread t = code t, sequential fp32 order (matches R1 prep) ----
    {
        const float* e = emb + (size_t)tid * DIM;
        float s = 0.f;
        #pragma unroll
        for (int d4 = 0; d4 < DIM; d4 += 4) {
            f32x4 v = *(const f32x4*)&e[d4];
            s += v.x * v.x; s += v.y * v.y; s += v.z * v.z; s += v.w * v.w;
        }
        esq_s[tid] = s;
    }

    // ---- stage + split codebook into LDS (once per block) ----
    #pragma unroll 4
    for (int i = 0; i < 16; ++i) {
        int f = tid + NTHREADS * i;                 // 0..8191
        int code = f >> 4, d4 = (f & 15) * 4;
        f32x4 v = *(const f32x4*)&emb[(size_t)code * DIM + d4];
        s16x4 hv, lv;
        #pragma unroll
        for (int j = 0; j < 4; ++j) {
            unsigned short h = f2bf(v[j]);
            hv[j] = (short)h;
            lv[j] = (short)f2bf(v[j] - bf2f(h));
        }
        *(s16x4*)&ehs[code * ESTR + d4] = hv;
        *(s16x4*)&els[code * ESTR + d4] = lv;
    }
    __syncthreads();

    float lpart = 0.f;
    const int waveRow0 = blockIdx.x * (NTHREADS / 64 * TILES * 32) + w * (TILES * 32);

    for (int t = 0; t < TILES; ++t) {
        const int T0 = waveRow0 + t * 32;

        // ---- x tile: global->reg (exact fp32 kept for epilogue) ----
        f32x4 xv[2][2][2];                          // [rg][kc][half]
        #pragma unroll
        for (int rg = 0; rg < 2; ++rg) {
            const float* px = &x[(size_t)(T0 + rg * 16 + m) * DIM + q * 8];
            xv[rg][0][0] = *(const f32x4*)&px[0];
            xv[rg][0][1] = *(const f32x4*)&px[4];
            xv[rg][1][0] = *(const f32x4*)&px[32];
            xv[rg][1][1] = *(const f32x4*)&px[36];
        }
        // ---- convert to bf16 hi/lo A-frags ----
        s16x8 axh[2][2], axl[2][2];
        #pragma unroll
        for (int rg = 0; rg < 2; ++rg)
            #pragma unroll
            for (int kc = 0; kc < 2; ++kc) {
                s16x8 h, l;
                #pragma unroll
                for (int hf = 0; hf < 2; ++hf)
                    #pragma unroll
                    for (int j = 0; j < 4; ++j) {
                        float v = xv[rg][kc][hf][j];
                        unsigned short hb = f2bf(v);
                        h[hf * 4 + j] = (short)hb;
                        l[hf * 4 + j] = (short)f2bf(v - bf2f(hb));
                    }
                axh[rg][kc] = h; axl[rg][kc] = l;
            }

        // ---- 4 passes of 128 codes; argmin folded per pass ----
        float b1[2][4], b2[2][4]; int i1[2][4];
        #pragma unroll
        for (int rg = 0; rg < 2; ++rg)
            #pragma unroll
            for (int r = 0; r < 4; ++r) { b1[rg][r] = 3.4e38f; b2[rg][r] = 3.4e38f; i1[rg][r] = 0; }

        for (int p = 0; p < 4; ++p) {
            f32x4 acc[2][8];
            #pragma unroll
            for (int rg = 0; rg < 2; ++rg)
                #pragma unroll
                for (int cg = 0; cg < 8; ++cg) acc[rg][cg] = (f32x4){0.f, 0.f, 0.f, 0.f};

            #pragma unroll
            for (int kc = 0; kc < 2; ++kc) {
                #pragma unroll
                for (int cg = 0; cg < 8; ++cg) {      // 8 independent 3-chains
                    const int off = (p * 128 + cg * 16 + m) * ESTR + kc * 32 + q * 8;
                    s16x8 bh = *(const s16x8*)&ehs[off];
                    s16x8 bl = *(const s16x8*)&els[off];
                    acc[0][cg] = __builtin_amdgcn_mfma_f32_16x16x32_bf16(axh[0][kc], bh, acc[0][cg], 0, 0, 0);
                    acc[0][cg] = __builtin_amdgcn_mfma_f32_16x16x32_bf16(axl[0][kc], bh, acc[0][cg], 0, 0, 0);
                    acc[0][cg] = __builtin_amdgcn_mfma_f32_16x16x32_bf16(axh[0][kc], bl, acc[0][cg], 0, 0, 0);
                    acc[1][cg] = __builtin_amdgcn_mfma_f32_16x16x32_bf16(axh[1][kc], bh, acc[1][cg], 0, 0, 0);
                    acc[1][cg] = __builtin_amdgcn_mfma_f32_16x16x32_bf16(axl[1][kc], bh, acc[1][cg], 0, 0, 0);
                    acc[1][cg] = __builtin_amdgcn_mfma_f32_16x16x32_bf16(axh[1][kc], bl, acc[1][cg], 0, 0, 0);
                }
            }
            // argmin update for this pass (C layout: row=q*4+r, col=p*128+cg*16+m)
            #pragma unroll
            for (int cg = 0; cg < 8; ++cg) {
                int col = p * 128 + cg * 16 + m;       // ascending overall
                float e2 = esq_s[col];
                #pragma unroll
                for (int rg = 0; rg < 2; ++rg)
                    #pragma unroll
                    for (int r = 0; r < 4; ++r) {
                        float dist = e2 - 2.f * acc[rg][cg][r];
                        if (dist < b1[rg][r]) { b2[rg][r] = b1[rg][r]; b1[rg][r] = dist; i1[rg][r] = col; }
                        else if (dist < b2[rg][r]) b2[rg][r] = dist;
                    }
            }
        }

        // ---- cross-lane (16 m-lanes) argmin + second-best combine ----
        #pragma unroll
        for (int s = 1; s < 16; s <<= 1) {
            #pragma unroll
            for (int rg = 0; rg < 2; ++rg)
                #pragma unroll
                for (int r = 0; r < 4; ++r) {
                    float ob1 = __shfl_xor(b1[rg][r], s);
                    int   oi1 = __shfl_xor(i1[rg][r], s);
                    float ob2 = __shfl_xor(b2[rg][r], s);
                    bool owin = (ob1 < b1[rg][r]) || (ob1 == b1[rg][r] && oi1 < i1[rg][r]);
                    float lb1 = owin ? b1[rg][r] : ob1;
                    b2[rg][r] = fminf(fminf(b2[rg][r], ob2), lb1);
                    if (owin) { b1[rg][r] = ob1; i1[rg][r] = oi1; }
                }
        }
        if (m == 0) {
            #pragma unroll
            for (int rg = 0; rg < 2; ++rg)
                #pragma unroll
                for (int r = 0; r < 4; ++r) {
                    int rl = rg * 16 + q * 4 + r;
                    int fl = (b2[rg][r] - b1[rg][r] < MARGIN) ? 1 : 0;
                    idx_sh[w][rl] = (unsigned short)i1[rg][r];
                    flg_sh[w][rl] = (unsigned short)fl;
                    if (fl) {
                        int grow = T0 + rl;
                        atomicOr(&g_mask[grow >> 5], 1u << (grow & 31));   // rare
                    }
                }
        }
        if (lane < 32) g_idx[T0 + lane] = idx_sh[w][lane];   // coalesced u16

        // ---- epilogue from registers (exact x), e gather from L2 ----
        #pragma unroll
        for (int rg = 0; rg < 2; ++rg) {
            int rl = rg * 16 + m;
            int ki = idx_sh[w][rl];
            int fl = flg_sh[w][rl];
            if (!fl) {
                const float* er = &emb[(size_t)ki * DIM + q * 8];
                float* po = &out[(size_t)(T0 + rl) * DIM + q * 8];
                #pragma unroll
                for (int kc = 0; kc < 2; ++kc)
                    #pragma unroll
                    for (int hf = 0; hf < 2; ++hf) {
                        f32x4 ev = *(const f32x4*)&er[kc * 32 + hf * 4];
                        f32x4 xvv = xv[rg][kc][hf];
                        f32x4 fd, o;
                        #pragma unroll
                        for (int j = 0; j < 4; ++j) {
                            fd[j] = ev[j] - xvv[j];
                            o[j]  = xvv[j] + fd[j];
                            lpart += fd[j] * fd[j];
                        }
                        *(f32x4*)&po[kc * 32 + hf * 4] = o;
                    }
            }
        }
    }

    // ---- block loss partial (no atomics) ----
    #pragma unroll
    for (int s = 32; s > 0; s >>= 1) lpart += __shfl_down(lpart, s);
    if (lane == 0) wred[w] = lpart;
    __syncthreads();
    if (tid == 0) {
        float s = 0.f;
        #pragma unroll
        for (int i = 0; i < 8; ++i) s += wred[i];
        g_lossPart[blockIdx.x] = s;
    }
}

// Fused: exact fp32 re-resolution of flagged rows (R1 math) + histogram.
__global__ __launch_bounds__(256) void vq_post(
    const float* __restrict__ x, const float* __restrict__ emb,
    unsigned short* __restrict__ g_idx, const unsigned* __restrict__ g_mask,
    float* __restrict__ out, int* __restrict__ counts2d,
    float* __restrict__ lossPost)
{
    __shared__ int h[KCODES];
    __shared__ float lred[4];
    const int b    = blockIdx.x;                 // 64 blocks, 4096 rows each
    const int tid  = threadIdx.x;
    const int wv   = tid >> 6;
    const int lane = tid & 63;

    // ---- phase A: resolve flagged rows in own slice ----
    float lp = 0.f;
    for (int wi = 0; wi < 32; ++wi) {
        unsigned mw = g_mask[b * 128 + wv * 32 + wi];
        while (mw) {
            int bit = __ffs(mw) - 1;
            mw &= mw - 1;
            int row = b * 4096 + wv * 1024 + wi * 32 + bit;
            const float* xr = &x[(size_t)row * DIM];
            float best = 3.4e38f; int bidx = 0;
            #pragma unroll
            for (int j = 0; j < 8; ++j) {
                int c = lane * 8 + j;
                const float* er = &emb[(size_t)c * DIM];
                float es = 0.f;
                #pragma unroll
                for (int d4 = 0; d4 < DIM; d4 += 4) {     // same order as esq above
                    f32x4 v = *(const f32x4*)&er[d4];
                    es += v.x * v.x; es += v.y * v.y; es += v.z * v.z; es += v.w * v.w;
                }
                float dot = 0.f;
                #pragma unroll
                for (int d = 0; d < DIM; ++d) dot = fmaf(xr[d], er[d], dot);
                float dist = es - 2.f * dot;              // R1 formula/order
                if (dist < best) { best = dist; bidx = c; }
            }
            #pragma unroll
            for (int s = 1; s < 64; s <<= 1) {
                float ob = __shfl_xor(best, s);
                int   oi = __shfl_xor(bidx, s);
                if (ob < best || (ob == best && oi < bidx)) { best = ob; bidx = oi; }
            }
            float xvv = xr[lane];
            float ev  = emb[(size_t)bidx * DIM + lane];
            float f   = ev - xvv;
            out[(size_t)row * DIM + lane] = xvv + f;
            lp += f * f;
            if (lane == 0) g_idx[row] = (unsigned short)bidx;
        }
    }
    #pragma unroll
    for (int s = 32; s > 0; s >>= 1) lp += __shfl_down(lp, s);
    if (lane == 0) lred[wv] = lp;
    __threadfence();
    __syncthreads();

    // ---- phase B: histogram own slice (reads incl. phase-A overwrites) ----
    h[tid] = 0; h[tid + 256] = 0;
    __syncthreads();
    const unsigned short* p = g_idx + (size_t)b * 4096;
    #pragma unroll
    for (int i = 0; i < 16; ++i)
        atomicAdd(&h[p[tid + 256 * i]], 1);
    __syncthreads();
    counts2d[b * KCODES + tid]       = h[tid];
    counts2d[b * KCODES + tid + 256] = h[tid + 256];
    if (tid == 0) lossPost[b] = lred[0] + lred[1] + lred[2] + lred[3];
}

__global__ __launch_bounds__(512) void vq_final(const int* __restrict__ counts2d,
                                                const float* __restrict__ lossPart,
                                                const float* __restrict__ lossPost,
                                                float* __restrict__ out) {
    __shared__ float redp[8], redl[8];
    int k = threadIdx.x;
    int c = 0;
    for (int b = 0; b < 64; ++b) c += counts2d[b * KCODES + k];
    float p = (float)c * (1.f / 262144.f);
    float t = p * logf(p + 1e-10f);
    float l = 0.f;
    if (k < 256) l = lossPart[k];
    if (k < 64)  l += lossPost[k];
    #pragma unroll
    for (int off = 32; off > 0; off >>= 1) {
        t += __shfl_down(t, off);
        l += __shfl_down(l, off);
    }
    if ((k & 63) == 0) { redp[k >> 6] = t; redl[k >> 6] = l; }
    __syncthreads();
    if (k == 0) {
        float s = 0.f, ls = 0.f;
        #pragma unroll
        for (int i = 0; i < 8; ++i) { s += redp[i]; ls += redl[i]; }
        out[16777216] = ls * (0.25f / 16777216.f);
        out[16777217] = expf(-s);
    }
}

extern "C" void kernel_launch(void* const* d_in, const int* in_sizes, int n_in,
                              void* d_out, int out_size, void* d_ws, size_t ws_size,
                              hipStream_t stream) {
    const float* x   = (const float*)d_in[0];
    const float* emb = (const float*)d_in[1];
    float* out = (float*)d_out;

    char* ws = (char*)d_ws;
    unsigned*       mask     = (unsigned*)(ws + 0);
    unsigned short* gidx     = (unsigned short*)(ws + 32768);
    float*          lossPart = (float*)(ws + 557056);
    float*          lossPost = (float*)(ws + 558080);
    int*            counts2d = (int*)(ws + 558336);

    vq_main<<<NBLOCKS, NTHREADS, 0, stream>>>(x, emb, gidx, lossPart, mask, out);
    vq_post<<<64, 256, 0, stream>>>(x, emb, gidx, mask, out, counts2d, lossPost);
    vq_final<<<1, 512, 0, stream>>>(counts2d, lossPart, lossPost, out);
}